// Round 4
// baseline (133.898 us; speedup 1.0000x reference)
//
#include <hip/hip_runtime.h>
#include <hip/hip_bf16.h>

// Problem constants (from setup_inputs): B=2, H=16, D=64, T=2048, MAX_N=64, R_TOK=4
#define BB   2
#define HH   16
#define DD   64
#define TT   2048
#define MAXN 64
#define RTOK 4
#define PP   (MAXN * RTOK)   // 256

// One block per (b, h, region). 256 threads = 4 waves; wave w owns query row w,
// lane = head dim. Keys for region r: 4 pool keys (unrotated, pos 0) followed by
// the contiguous sorted run of x-tokens with regions==r (RoPE pos = local+4).
// Inputs are fp32 storage (PROVEN round 3: dtype sniffer chose fp32 — output
// bit-identical to the unconditional-fp32 round 2). Output is therefore fp32
// too (reference returns float32; harness: "else float*").
__global__ __launch_bounds__(256)
void lapd_attn(const float* __restrict__ pool_q,
               const float* __restrict__ pool_k,
               const float* __restrict__ pool_v,
               const float* __restrict__ x_k,
               const float* __restrict__ x_v,
               const int* __restrict__ regions,
               float* __restrict__ out) {
    const int blk   = blockIdx.x;          // b*H*MAXN + h*MAXN + (r-1)
    const int r_idx = blk & (MAXN - 1);
    const int bh    = blk >> 6;            // b*H + h
    const int r     = r_idx + 1;
    const int b     = bh / HH;

    // Binary search the sorted regions[b, :] for [start, start+cnt) of region r.
    const int* reg_b = regions + b * TT;
    int lo = 0, hi = TT;
    while (lo < hi) { int mid = (lo + hi) >> 1; if (reg_b[mid] < r) lo = mid + 1; else hi = mid; }
    const int start = lo;
    hi = TT;
    while (lo < hi) { int mid = (lo + hi) >> 1; if (reg_b[mid] <= r) lo = mid + 1; else hi = mid; }
    const int cnt    = lo - start;
    const int n_keys = RTOK + cnt;

    const int tid  = threadIdx.x;
    const int wave = tid >> 6;   // query row 0..3
    const int lane = tid & 63;   // head dim

    const size_t poolbase = ((size_t)bh * PP + r_idx * RTOK) * DD;
    const size_t xbase    = (size_t)bh * TT * DD;

    // Pool queries are at RoPE pos 0 -> unrotated. Fold 1/sqrt(64) into q.
    const size_t qidx = poolbase + (size_t)(wave * DD) + lane;
    const float qv = pool_q[qidx] * 0.125f;

    float m = -1e30f, l = 0.0f, acc = 0.0f;

    __shared__ float k_s[64][DD];   // 16 KB
    __shared__ float v_s[64][DD];   // 16 KB

    const float* pk = pool_k + poolbase;
    const float* pv = pool_v + poolbase;
    const float* xk = x_k + xbase;
    const float* xv = x_v + xbase;

    for (int tile = 0; tile < n_keys; tile += 64) {
        const int tn = min(64, n_keys - tile);
        __syncthreads();
        // Stage tn keys+values into LDS; rotate x keys during load.
        // flat element id over [tn x 64]; each thread does 4 consecutive dims
        // (float4 = 16B aligned loads, fully coalesced across the wave).
        for (int base = 0; base < tn * DD; base += 1024) {
            const int flat = base + tid * 4;
            if (flat < tn * DD) {
                const int key = flat >> 6;
                const int dim = flat & 63;
                const int gk  = tile + key;            // region-local key index
                if (gk < RTOK) {                       // pool key, pos 0: no rotation
                    *(float4*)&k_s[key][dim] = *(const float4*)(pk + gk * DD + dim);
                    *(float4*)&v_s[key][dim] = *(const float4*)(pv + gk * DD + dim);
                } else {                               // x key: RoPE at pos = gk
                    const size_t off = (size_t)(start + gk - RTOK) * DD;
                    const float4 kv = *(const float4*)(xk + off + dim);
                    const float4 kp = *(const float4*)(xk + off + ((dim + 32) & 63));
                    const float4 vv = *(const float4*)(xv + off + dim);
                    // local pos = (gk-4), RoPE pos = local + R_TOK = gk
                    const float pos = (float)gk;
                    // split-half convention: rot(x)[j] = -x[j+32] (j<32), +x[j-32] (j>=32)
                    const float sgn = (dim < 32) ? -1.0f : 1.0f;
                    const float kd[4]  = {kv.x, kv.y, kv.z, kv.w};
                    const float kpd[4] = {kp.x, kp.y, kp.z, kp.w};
                    float kr[4];
                    #pragma unroll
                    for (int c = 0; c < 4; ++c) {
                        const int j = (dim + c) & 31;
                        // inv_freq[j] = theta^(-j/32), ln(10000)=9.2103403719...
                        const float invf = __expf((float)j * (-9.210340371976184f / 32.0f));
                        float sv, cv;
                        sincosf(pos * invf, &sv, &cv);
                        kr[c] = kd[c] * cv + sgn * kpd[c] * sv;
                    }
                    *(float4*)&k_s[key][dim] = make_float4(kr[0], kr[1], kr[2], kr[3]);
                    *(float4*)&v_s[key][dim] = vv;
                }
            }
        }
        __syncthreads();
        // Online softmax over this tile; each wave scans keys serially.
        for (int key = 0; key < tn; ++key) {
            float prod = qv * k_s[key][lane];
            #pragma unroll
            for (int off = 32; off > 0; off >>= 1)
                prod += __shfl_xor(prod, off, 64);
            const float s     = prod;                 // scale already folded into q
            const float m_new = fmaxf(m, s);
            const float alpha = __expf(m - m_new);
            const float p     = __expf(s - m_new);
            l   = l * alpha + p;
            acc = acc * alpha + p * v_s[key][lane];
            m   = m_new;
        }
    }

    out[qidx] = acc / l;
}

extern "C" void kernel_launch(void* const* d_in, const int* in_sizes, int n_in,
                              void* d_out, int out_size, void* d_ws, size_t ws_size,
                              hipStream_t stream) {
    // setup_inputs order: pool_q, pool_k, pool_v, x_q(unused), x_k, x_v,
    //                     regions, t_mask(unused, all-true), n_mask(unused), max_n(unused)
    const float* pool_q  = (const float*)d_in[0];
    const float* pool_k  = (const float*)d_in[1];
    const float* pool_v  = (const float*)d_in[2];
    const float* x_k     = (const float*)d_in[4];
    const float* x_v     = (const float*)d_in[5];
    const int*   regions = (const int*)d_in[6];
    float*       out     = (float*)d_out;

    lapd_attn<<<dim3(BB * HH * MAXN), dim3(256), 0, stream>>>(
        pool_q, pool_k, pool_v, x_k, x_v, regions, out);
}

// Round 5
// 121.617 us; speedup vs baseline: 1.1010x; 1.1010x over previous
//
#include <hip/hip_runtime.h>
#include <hip/hip_bf16.h>

// Problem constants (from setup_inputs): B=2, H=16, D=64, T=2048, MAX_N=64, R_TOK=4
#define BB   2
#define HH   16
#define DD   64
#define TT   2048
#define MAXN 64
#define RTOK 4
#define PP   (MAXN * RTOK)   // 256

// One block per (b, h, region). 256 threads = 4 waves; wave w owns query row w.
// Round-5 restructure (round 4 proved latency-bound, not HBM-bound: L3-hot
// replay ran at identical 43.5us):
//  - scores with lane=key (one shuffle-reduction pair per TILE, not per key)
//  - PV straight from global (coalesced, L1-cached across the 4 waves)
//  - region range via cooperative count (1 memory round-trip, not 22 serial)
//  - fast __sincosf
__global__ __launch_bounds__(256, 8)
void lapd_attn(const float* __restrict__ pool_q,
               const float* __restrict__ pool_k,
               const float* __restrict__ pool_v,
               const float* __restrict__ x_k,
               const float* __restrict__ x_v,
               const int* __restrict__ regions,
               float* __restrict__ out) {
    const int blk   = blockIdx.x;          // b*H*MAXN + h*MAXN + (r-1)
    const int r_idx = blk & (MAXN - 1);
    const int bh    = blk >> 6;            // b*H + h
    const int r     = r_idx + 1;
    const int b     = bh / HH;

    const int tid  = threadIdx.x;
    const int wave = tid >> 6;   // query row 0..3
    const int lane = tid & 63;

    __shared__ float k_s[64][DD + 1];   // pad -> bank (k+d)%32, 2-way free
    __shared__ float q_s[4][DD];
    __shared__ float p_s[4][64];
    __shared__ int   cnt_s[4];

    // ---- region range [start, start+cnt) via cooperative count ----
    // regions[b] is sorted; count (<r, <=r) packed in one int (each <= 2048).
    {
        const int4* reg4 = (const int4*)(regions + b * TT);
        int c_lt = 0, c_le = 0;
        #pragma unroll
        for (int i = 0; i < 2; ++i) {
            const int4 v = reg4[tid + i * 256];
            c_lt += (v.x <  r) + (v.y <  r) + (v.z <  r) + (v.w <  r);
            c_le += (v.x <= r) + (v.y <= r) + (v.z <= r) + (v.w <= r);
        }
        int packed = c_lt | (c_le << 16);
        #pragma unroll
        for (int off = 32; off > 0; off >>= 1)
            packed += __shfl_xor(packed, off, 64);
        if (lane == 0) cnt_s[wave] = packed;
    }
    __syncthreads();
    const int tot    = cnt_s[0] + cnt_s[1] + cnt_s[2] + cnt_s[3];
    const int start  = tot & 0xFFFF;
    const int n_keys = ((tot >> 16) & 0xFFFF) - start + RTOK;

    const size_t poolbase = ((size_t)bh * PP + r_idx * RTOK) * DD;
    const float* pk = pool_k + poolbase;
    const float* pv = pool_v + poolbase;
    const float* xk = x_k + (size_t)bh * TT * DD;
    const float* xv = x_v + (size_t)bh * TT * DD;

    // Pool queries at RoPE pos 0 -> unrotated. Fold 1/sqrt(64) into q.
    q_s[wave][lane] = pool_q[poolbase + (size_t)(wave * DD) + lane] * 0.125f;
    // (wave-private write/read: no barrier needed)

    float m = -1e30f, l = 0.0f, acc = 0.0f;

    for (int tile = 0; tile < n_keys; tile += 64) {
        const int tn = min(64, n_keys - tile);
        __syncthreads();   // protect k_s from previous tile's readers
        // ---- stage rotated K into LDS (float4 global loads, scalar LDS writes) ----
        for (int base = 0; base < tn * DD; base += 1024) {
            const int flat = base + tid * 4;
            if (flat < tn * DD) {
                const int key = flat >> 6;
                const int dim = flat & 63;
                const int gk  = tile + key;            // region-local key index
                float kr[4];
                if (gk < RTOK) {                       // pool key, pos 0: no rotation
                    const float4 kv = *(const float4*)(pk + gk * DD + dim);
                    kr[0] = kv.x; kr[1] = kv.y; kr[2] = kv.z; kr[3] = kv.w;
                } else {                               // x key: RoPE at pos = gk
                    const size_t off = (size_t)(start + gk - RTOK) * DD;
                    const float4 kv = *(const float4*)(xk + off + dim);
                    const float4 kp = *(const float4*)(xk + off + ((dim + 32) & 63));
                    const float pos = (float)gk;       // local pos (gk-4) + R_TOK
                    const float sgn = (dim < 32) ? -1.0f : 1.0f;
                    const float kd[4]  = {kv.x, kv.y, kv.z, kv.w};
                    const float kpd[4] = {kp.x, kp.y, kp.z, kp.w};
                    #pragma unroll
                    for (int c = 0; c < 4; ++c) {
                        const int j = (dim + c) & 31;
                        const float invf = __expf((float)j * (-9.210340371976184f / 32.0f));
                        float sv, cv;
                        __sincosf(pos * invf, &sv, &cv);
                        kr[c] = kd[c] * cv + sgn * kpd[c] * sv;
                    }
                }
                k_s[key][dim + 0] = kr[0];
                k_s[key][dim + 1] = kr[1];
                k_s[key][dim + 2] = kr[2];
                k_s[key][dim + 3] = kr[3];
            }
        }
        __syncthreads();

        // ---- scores: lane = key ----
        float s = -1e30f;
        if (lane < tn) {
            float s0 = 0, s1 = 0, s2 = 0, s3 = 0;
            #pragma unroll
            for (int d = 0; d < DD; d += 4) {
                s0 += q_s[wave][d + 0] * k_s[lane][d + 0];
                s1 += q_s[wave][d + 1] * k_s[lane][d + 1];
                s2 += q_s[wave][d + 2] * k_s[lane][d + 2];
                s3 += q_s[wave][d + 3] * k_s[lane][d + 3];
            }
            s = (s0 + s1) + (s2 + s3);
        }
        // ---- one softmax reduction pair per tile ----
        float tm = s;
        #pragma unroll
        for (int off = 32; off > 0; off >>= 1)
            tm = fmaxf(tm, __shfl_xor(tm, off, 64));
        const float m_new = fmaxf(m, tm);
        const float alpha = __expf(m - m_new);
        const float p = (lane < tn) ? __expf(s - m_new) : 0.0f;
        float ts = p;
        #pragma unroll
        for (int off = 32; off > 0; off >>= 1)
            ts += __shfl_xor(ts, off, 64);
        l = l * alpha + ts;
        m = m_new;
        p_s[wave][lane] = p;   // wave-private transpose (no barrier needed)

        // ---- PV: lane = dim, coalesced global v reads (L1-shared by 4 waves) ----
        acc *= alpha;
        int k = 0;
        if (tile == 0) {
            #pragma unroll
            for (int kk = 0; kk < RTOK; ++kk)
                acc += p_s[wave][kk] * pv[kk * DD + lane];
            k = RTOK;
        }
        float a0 = 0, a1 = 0, a2 = 0, a3 = 0;
        for (; k + 3 < tn; k += 4) {
            const size_t o = (size_t)(start + tile + k - RTOK) * DD + lane;
            a0 += p_s[wave][k + 0] * xv[o];
            a1 += p_s[wave][k + 1] * xv[o + DD];
            a2 += p_s[wave][k + 2] * xv[o + 2 * DD];
            a3 += p_s[wave][k + 3] * xv[o + 3 * DD];
        }
        for (; k < tn; ++k)
            acc += p_s[wave][k] * xv[(size_t)(start + tile + k - RTOK) * DD + lane];
        acc += (a0 + a1) + (a2 + a3);
    }

    out[poolbase + (size_t)(wave * DD) + lane] = acc / l;
}

extern "C" void kernel_launch(void* const* d_in, const int* in_sizes, int n_in,
                              void* d_out, int out_size, void* d_ws, size_t ws_size,
                              hipStream_t stream) {
    // setup_inputs order: pool_q, pool_k, pool_v, x_q(unused), x_k, x_v,
    //                     regions, t_mask(unused, all-true), n_mask(unused), max_n(unused)
    const float* pool_q  = (const float*)d_in[0];
    const float* pool_k  = (const float*)d_in[1];
    const float* pool_v  = (const float*)d_in[2];
    const float* x_k     = (const float*)d_in[4];
    const float* x_v     = (const float*)d_in[5];
    const int*   regions = (const int*)d_in[6];
    float*       out     = (float*)d_out;

    lapd_attn<<<dim3(BB * HH * MAXN), dim3(256), 0, stream>>>(
        pool_q, pool_k, pool_v, x_k, x_v, regions, out);
}

// Round 6
// 119.650 us; speedup vs baseline: 1.1191x; 1.0164x over previous
//
#include <hip/hip_runtime.h>
#include <hip/hip_bf16.h>

// Problem constants (from setup_inputs): B=2, H=16, D=64, T=2048, MAX_N=64, R_TOK=4
#define BB   2
#define HH   16
#define DD   64
#define TT   2048
#define MAXN 64
#define RTOK 4
#define PP   (MAXN * RTOK)   // 256
#define KPAD 65              // row pad: bank (k+d)%32, 2-way aliasing = free

// One block per (b, h, region). 256 threads = 4 waves; wave w owns query row w.
// Round 6: the kernel is memory-latency bound (R4: L3-hot replay same speed as
// cold; ~500 GB/s achieved). Fix = one deep load burst: K AND V staged to LDS,
// all global loads batched into registers before any processing; PV from LDS.
__global__ __launch_bounds__(256, 4)
void lapd_attn(const float* __restrict__ pool_q,
               const float* __restrict__ pool_k,
               const float* __restrict__ pool_v,
               const float* __restrict__ x_k,
               const float* __restrict__ x_v,
               const int* __restrict__ regions,
               float* __restrict__ out) {
    const int blk   = blockIdx.x;          // b*H*MAXN + h*MAXN + (r-1)
    const int r_idx = blk & (MAXN - 1);
    const int bh    = blk >> 6;            // b*H + h
    const int r     = r_idx + 1;
    const int b     = bh / HH;

    const int tid  = threadIdx.x;
    const int wave = tid >> 6;   // query row 0..3
    const int lane = tid & 63;

    __shared__ float k_s[64][KPAD];   // 16.6 KB
    __shared__ float v_s[64][KPAD];   // 16.6 KB
    __shared__ float q_s[4][DD];
    __shared__ float p_s[4][64];
    __shared__ int   cnt_s[4];

    const size_t poolbase = ((size_t)bh * PP + r_idx * RTOK) * DD;
    const float* pk = pool_k + poolbase;
    const float* pv = pool_v + poolbase;
    const float* xk = x_k + (size_t)bh * TT * DD;
    const float* xv = x_v + (size_t)bh * TT * DD;

    // Pool queries at RoPE pos 0 -> unrotated; fold 1/sqrt(64) into q.
    // Issued BEFORE the count phase (independent of it) for load overlap.
    const size_t qidx = poolbase + (size_t)(wave * DD) + lane;
    const float qv = pool_q[qidx] * 0.125f;
    q_s[wave][lane] = qv;    // wave-private write/read: no barrier needed

    // ---- region range [start, start+cnt) via cooperative count ----
    // regions[b] is sorted; count (<r, <=r) packed in one int (each <= 2048).
    {
        const int4* reg4 = (const int4*)(regions + b * TT);
        int c_lt = 0, c_le = 0;
        #pragma unroll
        for (int i = 0; i < 2; ++i) {
            const int4 v = reg4[tid + i * 256];
            c_lt += (v.x <  r) + (v.y <  r) + (v.z <  r) + (v.w <  r);
            c_le += (v.x <= r) + (v.y <= r) + (v.z <= r) + (v.w <= r);
        }
        int packed = c_lt | (c_le << 16);
        #pragma unroll
        for (int off = 32; off > 0; off >>= 1)
            packed += __shfl_xor(packed, off, 64);
        if (lane == 0) cnt_s[wave] = packed;
    }
    __syncthreads();
    const int tot    = cnt_s[0] + cnt_s[1] + cnt_s[2] + cnt_s[3];
    const int start  = tot & 0xFFFF;
    const int n_keys = ((tot >> 16) & 0xFFFF) - start + RTOK;

    float m = -1e30f, l = 0.0f, acc = 0.0f;

    for (int tile = 0; tile < n_keys; tile += 64) {
        const int tn = min(64, n_keys - tile);
        __syncthreads();   // protect k_s/v_s from previous tile's readers

        // ---- load burst: ALL global loads for this tile issued back-to-back
        // into registers (up to 12 x 16B outstanding per thread), THEN process.
        float4 kvb[4], kpb[4], vvb[4];
        #pragma unroll
        for (int p = 0; p < 4; ++p) {
            const int flat = p * 1024 + tid * 4;
            if (flat < tn * DD) {
                const int key = flat >> 6;
                const int dim = flat & 63;
                const int gk  = tile + key;            // region-local key index
                if (gk < RTOK) {                       // pool row, pos 0
                    kvb[p] = *(const float4*)(pk + gk * DD + dim);
                    kpb[p] = kvb[p];                   // unused for pool rows
                    vvb[p] = *(const float4*)(pv + gk * DD + dim);
                } else {                               // x row
                    const size_t off = (size_t)(start + gk - RTOK) * DD;
                    kvb[p] = *(const float4*)(xk + off + dim);
                    kpb[p] = *(const float4*)(xk + off + ((dim + 32) & 63));
                    vvb[p] = *(const float4*)(xv + off + dim);
                }
            }
        }
        // ---- process: RoPE-rotate K (x rows only), write K and V to LDS ----
        #pragma unroll
        for (int p = 0; p < 4; ++p) {
            const int flat = p * 1024 + tid * 4;
            if (flat < tn * DD) {
                const int key = flat >> 6;
                const int dim = flat & 63;
                const int gk  = tile + key;
                float kr[4] = {kvb[p].x, kvb[p].y, kvb[p].z, kvb[p].w};
                if (gk >= RTOK) {
                    // local pos = (gk-4), RoPE pos = local + R_TOK = gk
                    const float pos = (float)gk;
                    // split-half: rot(x)[j] = -x[j+32] (j<32), +x[j-32] (j>=32)
                    const float sgn = (dim < 32) ? -1.0f : 1.0f;
                    const float kpd[4] = {kpb[p].x, kpb[p].y, kpb[p].z, kpb[p].w};
                    #pragma unroll
                    for (int c = 0; c < 4; ++c) {
                        const int j = (dim + c) & 31;
                        const float invf = __expf((float)j * (-9.210340371976184f / 32.0f));
                        float sv, cv;
                        __sincosf(pos * invf, &sv, &cv);
                        kr[c] = kr[c] * cv + sgn * kpd[c] * sv;
                    }
                }
                k_s[key][dim + 0] = kr[0];
                k_s[key][dim + 1] = kr[1];
                k_s[key][dim + 2] = kr[2];
                k_s[key][dim + 3] = kr[3];
                v_s[key][dim + 0] = vvb[p].x;
                v_s[key][dim + 1] = vvb[p].y;
                v_s[key][dim + 2] = vvb[p].z;
                v_s[key][dim + 3] = vvb[p].w;
            }
        }
        __syncthreads();

        // ---- scores: lane = key (bank (lane+d)%32: conflict-free) ----
        float s = -1e30f;
        if (lane < tn) {
            float s0 = 0, s1 = 0, s2 = 0, s3 = 0;
            #pragma unroll
            for (int d = 0; d < DD; d += 4) {
                s0 += q_s[wave][d + 0] * k_s[lane][d + 0];
                s1 += q_s[wave][d + 1] * k_s[lane][d + 1];
                s2 += q_s[wave][d + 2] * k_s[lane][d + 2];
                s3 += q_s[wave][d + 3] * k_s[lane][d + 3];
            }
            s = (s0 + s1) + (s2 + s3);
        }
        // ---- one softmax reduction pair per tile ----
        float tm = s;
        #pragma unroll
        for (int off = 32; off > 0; off >>= 1)
            tm = fmaxf(tm, __shfl_xor(tm, off, 64));
        const float m_new = fmaxf(m, tm);
        const float alpha = __expf(m - m_new);
        const float p = (lane < tn) ? __expf(s - m_new) : 0.0f;
        float ts = p;
        #pragma unroll
        for (int off = 32; off > 0; off >>= 1)
            ts += __shfl_xor(ts, off, 64);
        l = l * alpha + ts;
        m = m_new;
        p_s[wave][lane] = p;   // wave-private transpose (no barrier needed)

        // ---- PV from LDS: lane = dim; v_s[k][lane] bank (k+lane)%32 = free,
        // p_s[wave][k] is a broadcast read ----
        acc *= alpha;
        float a0 = 0, a1 = 0, a2 = 0, a3 = 0;
        int k = 0;
        for (; k + 3 < tn; k += 4) {
            a0 += p_s[wave][k + 0] * v_s[k + 0][lane];
            a1 += p_s[wave][k + 1] * v_s[k + 1][lane];
            a2 += p_s[wave][k + 2] * v_s[k + 2][lane];
            a3 += p_s[wave][k + 3] * v_s[k + 3][lane];
        }
        for (; k < tn; ++k)
            acc += p_s[wave][k] * v_s[k][lane];
        acc += (a0 + a1) + (a2 + a3);
    }

    out[qidx] = acc / l;
}

extern "C" void kernel_launch(void* const* d_in, const int* in_sizes, int n_in,
                              void* d_out, int out_size, void* d_ws, size_t ws_size,
                              hipStream_t stream) {
    // setup_inputs order: pool_q, pool_k, pool_v, x_q(unused), x_k, x_v,
    //                     regions, t_mask(unused, all-true), n_mask(unused), max_n(unused)
    const float* pool_q  = (const float*)d_in[0];
    const float* pool_k  = (const float*)d_in[1];
    const float* pool_v  = (const float*)d_in[2];
    const float* x_k     = (const float*)d_in[4];
    const float* x_v     = (const float*)d_in[5];
    const int*   regions = (const int*)d_in[6];
    float*       out     = (float*)d_out;

    lapd_attn<<<dim3(BB * HH * MAXN), dim3(256), 0, stream>>>(
        pool_q, pool_k, pool_v, x_k, x_v, regions, out);
}

// Round 7
// 114.354 us; speedup vs baseline: 1.1709x; 1.0463x over previous
//
#include <hip/hip_runtime.h>
#include <hip/hip_bf16.h>

// Problem constants (from setup_inputs): B=2, H=16, D=64, T=2048, MAX_N=64, R_TOK=4
#define BB   2
#define HH   16
#define DD   64
#define TT   2048
#define MAXN 64
#define RTOK 4
#define PP   (MAXN * RTOK)   // 256
#define PAD  68              // row pad: 272 B rows -> 16B-aligned b128, even bank tiling

// ---------------------------------------------------------------------------
// Kernel 1: region range table. tab[b][r] = first index i with regions[b][i] >= r
// (r = 1..64); tab[b][65] = TT. Sorted input -> boundary detection, each slot
// written exactly once. 2 blocks x 256 threads, ~1-2 us.
// ---------------------------------------------------------------------------
__global__ __launch_bounds__(256)
void build_ranges(const int* __restrict__ regions, int* __restrict__ tab) {
    const int b   = blockIdx.x;
    const int tid = threadIdx.x;
    const int* reg = regions + b * TT;
    int* t = tab + b * 66;
    const int i0 = tid * 8;
    int v[9];
    const int4 a0 = *(const int4*)(reg + i0);
    const int4 a1 = *(const int4*)(reg + i0 + 4);
    v[0] = a0.x; v[1] = a0.y; v[2] = a0.z; v[3] = a0.w;
    v[4] = a1.x; v[5] = a1.y; v[6] = a1.z; v[7] = a1.w;
    v[8] = (tid == 255) ? (MAXN + 1) : reg[i0 + 8];
    if (tid == 0)
        for (int rr = 1; rr <= v[0]; ++rr) t[rr] = 0;
    #pragma unroll
    for (int j = 0; j < 8; ++j)
        for (int rr = v[j] + 1; rr <= v[j + 1]; ++rr) t[rr] = i0 + j + 1;
}

// ---------------------------------------------------------------------------
// Stage nrows x-rows (region-local x index xbase..) into LDS keys koff.. :
// K RoPE-rotated into k_s[key][dim], V transposed into v_t[dim][key].
// Rows >= nx are clamped to row nx-1 (duplicates; their p will be 0).
// RoPE partner half comes from lane^8 via shuffle (same row, dim^32).
// ---------------------------------------------------------------------------
__device__ __forceinline__ void stage_x(const float* __restrict__ xk,
                                        const float* __restrict__ xv,
                                        int start, int xbase, int nx, int koff,
                                        int nrows, int tid,
                                        float (*k_s)[PAD], float (*v_t)[PAD]) {
    float4 kv[4], vv[4];
    int dim[4], xi_u[4];
    // ---- burst: all global loads issued back-to-back ----
    #pragma unroll
    for (int p = 0; p < 4; ++p) {
        const int flat = p * 1024 + tid * 4;
        xi_u[p] = flat >> 6;                       // unclamped local x index
        dim[p]  = flat & 63;
        const int xi = min(xi_u[p], nx - 1);       // clamp -> always in-bounds
        const size_t off = (size_t)(start + xbase + xi) * DD;
        kv[p] = *(const float4*)(xk + off + dim[p]);
        vv[p] = *(const float4*)(xv + off + dim[p]);
    }
    // ---- process: rotate K, write K + transposed V ----
    #pragma unroll
    for (int p = 0; p < 4; ++p) {
        float4 kp;                                  // dims dim^32 of the same row
        kp.x = __shfl_xor(kv[p].x, 8, 64);
        kp.y = __shfl_xor(kv[p].y, 8, 64);
        kp.z = __shfl_xor(kv[p].z, 8, 64);
        kp.w = __shfl_xor(kv[p].w, 8, 64);
        const int key = koff + xi_u[p];
        if (key < 64) {                             // only tile-0 trims (nrows=60)
            const int d = dim[p];
            // RoPE pos = local_x_index + RTOK (any finite value ok for clamped rows)
            const float pos = (float)(xbase + xi_u[p] + RTOK);
            const float sgn = (d < 32) ? -1.0f : 1.0f;
            const float kd[4]  = {kv[p].x, kv[p].y, kv[p].z, kv[p].w};
            const float kpd[4] = {kp.x, kp.y, kp.z, kp.w};
            float kr[4];
            #pragma unroll
            for (int c = 0; c < 4; ++c) {
                const int j = (d + c) & 31;
                const float invf = __expf((float)j * (-9.210340371976184f / 32.0f));
                float sv, cv;
                __sincosf(pos * invf, &sv, &cv);
                kr[c] = kd[c] * cv + sgn * kpd[c] * sv;
            }
            *(float4*)&k_s[key][d] = make_float4(kr[0], kr[1], kr[2], kr[3]);
            v_t[d + 0][key] = vv[p].x;
            v_t[d + 1][key] = vv[p].y;
            v_t[d + 2][key] = vv[p].z;
            v_t[d + 3][key] = vv[p].w;
        }
    }
}

// ---------------------------------------------------------------------------
// Main kernel: one block per (b, h, region); 4 waves, wave = query row,
// lane = key (scores) / dim (PV). Range from precomputed table (scalar load).
// ---------------------------------------------------------------------------
__global__ __launch_bounds__(256, 4)
void lapd_attn(const float* __restrict__ pool_q,
               const float* __restrict__ pool_k,
               const float* __restrict__ pool_v,
               const float* __restrict__ x_k,
               const float* __restrict__ x_v,
               const int* __restrict__ tab,
               float* __restrict__ out) {
    const int blk   = blockIdx.x;          // b*H*MAXN + h*MAXN + (r-1)
    const int r_idx = blk & (MAXN - 1);
    const int bh    = blk >> 6;            // b*H + h
    const int b     = bh / HH;

    const int tid  = threadIdx.x;
    const int wave = tid >> 6;   // query row 0..3
    const int lane = tid & 63;

    __shared__ float k_s[64][PAD];   // 17.4 KB
    __shared__ float v_t[64][PAD];   // 17.4 KB (transposed: v_t[dim][key])
    __shared__ float q_s[4][DD];
    __shared__ float p_s[4][64];

    // Wave-uniform range read (scalar loads; table is L2-hot).
    const int* tb   = tab + b * 66;
    const int start = tb[r_idx + 1];
    const int cnt   = tb[r_idx + 2] - start;

    const size_t poolbase = ((size_t)bh * PP + r_idx * RTOK) * DD;
    const float* pk = pool_k + poolbase;
    const float* pv = pool_v + poolbase;
    const float* xk = x_k + (size_t)bh * TT * DD;
    const float* xv = x_v + (size_t)bh * TT * DD;

    // Pool queries at RoPE pos 0 -> unrotated; fold 1/sqrt(64) into q.
    const size_t qidx = poolbase + (size_t)(wave * DD) + lane;
    const float qv = pool_q[qidx] * 0.125f;
    q_s[wave][lane] = qv;    // wave-private write/read: no barrier needed

    // Pool K/V rows (keys 0..3): threads 0..63, no RoPE.
    if (tid < 64) {
        const int key = tid >> 4, d = (tid & 15) * 4;
        const float4 kvp = *(const float4*)(pk + key * DD + d);
        const float4 vvp = *(const float4*)(pv + key * DD + d);
        *(float4*)&k_s[key][d] = kvp;
        v_t[d + 0][key] = vvp.x;
        v_t[d + 1][key] = vvp.y;
        v_t[d + 2][key] = vvp.z;
        v_t[d + 3][key] = vvp.w;
    }

    int tn, xbase;
    if (cnt > 0) {
        const int nx0 = min(cnt, 60);
        stage_x(xk, xv, start, 0, nx0, RTOK, 60, tid, k_s, v_t);
        tn = RTOK + nx0;
        xbase = nx0;
    } else {
        // empty region (essentially never): zero-fill rows 4..63 so PV reads 0s
        for (int i = tid; i < 60 * DD; i += 256) {
            const int key = 4 + (i >> 6), d = i & 63;
            k_s[key][d] = 0.0f;
            v_t[d][key] = 0.0f;
        }
        tn = RTOK;
        xbase = 0;
    }

    float m = -1e30f, l = 0.0f, acc = 0.0f;

    for (;;) {
        __syncthreads();   // staging visible to all waves

        // ---- scores: lane = key; b128 LDS reads (aligned, even bank tiling) ----
        float s = -1e30f;
        if (lane < tn) {
            float s0 = 0, s1 = 0, s2 = 0, s3 = 0;
            #pragma unroll
            for (int d = 0; d < DD; d += 4) {
                const float4 kk = *(const float4*)&k_s[lane][d];
                s0 += q_s[wave][d + 0] * kk.x;
                s1 += q_s[wave][d + 1] * kk.y;
                s2 += q_s[wave][d + 2] * kk.z;
                s3 += q_s[wave][d + 3] * kk.w;
            }
            s = (s0 + s1) + (s2 + s3);
        }
        // ---- one softmax reduction pair per tile ----
        float tm = s;
        #pragma unroll
        for (int off = 32; off > 0; off >>= 1)
            tm = fmaxf(tm, __shfl_xor(tm, off, 64));
        const float m_new = fmaxf(m, tm);
        const float alpha = __expf(m - m_new);
        const float p = (lane < tn) ? __expf(s - m_new) : 0.0f;
        float ts = p;
        #pragma unroll
        for (int off = 32; off > 0; off >>= 1)
            ts += __shfl_xor(ts, off, 64);
        l = l * alpha + ts;
        m = m_new;
        p_s[wave][lane] = p;   // all 64 entries written每 tile (0 beyond tn)

        // ---- PV: lane = dim; b128 reads of v_t[lane][k..k+3] ----
        acc *= alpha;
        float a0 = 0, a1 = 0, a2 = 0, a3 = 0;
        #pragma unroll
        for (int k = 0; k < 64; k += 4) {
            const float4 vv4 = *(const float4*)&v_t[lane][k];
            a0 += p_s[wave][k + 0] * vv4.x;
            a1 += p_s[wave][k + 1] * vv4.y;
            a2 += p_s[wave][k + 2] * vv4.z;
            a3 += p_s[wave][k + 3] * vv4.w;
        }
        acc += (a0 + a1) + (a2 + a3);

        if (xbase >= cnt) break;
        __syncthreads();   // all waves done reading before restage (rare: cnt>60)
        const int nx = min(64, cnt - xbase);
        stage_x(xk, xv, start, xbase, nx, 0, 64, tid, k_s, v_t);
        tn = nx;
        xbase += nx;
    }

    out[qidx] = acc / l;
}

extern "C" void kernel_launch(void* const* d_in, const int* in_sizes, int n_in,
                              void* d_out, int out_size, void* d_ws, size_t ws_size,
                              hipStream_t stream) {
    // setup_inputs order: pool_q, pool_k, pool_v, x_q(unused), x_k, x_v,
    //                     regions, t_mask(unused, all-true), n_mask(unused), max_n(unused)
    const float* pool_q  = (const float*)d_in[0];
    const float* pool_k  = (const float*)d_in[1];
    const float* pool_v  = (const float*)d_in[2];
    const float* x_k     = (const float*)d_in[4];
    const float* x_v     = (const float*)d_in[5];
    const int*   regions = (const int*)d_in[6];
    float*       out     = (float*)d_out;
    int*         tab     = (int*)d_ws;    // 2*66 ints, rebuilt every launch

    build_ranges<<<dim3(BB), dim3(256), 0, stream>>>(regions, tab);
    lapd_attn<<<dim3(BB * HH * MAXN), dim3(256), 0, stream>>>(
        pool_q, pool_k, pool_v, x_k, x_v, tab, out);
}